// Round 11
// baseline (274.941 us; speedup 1.0000x reference)
//
#include <hip/hip_runtime.h>
#include <math.h>

// Problem constants
#define BB    64
#define NEC   40000
#define NRC   500
#define D1C   200
#define D2C   200
#define LLC   64
#define BN_EPS 1e-5f
#define LOG2E 1.4426950408889634f

// ws layout (floats):
//   xT    [D1][64]        @ 0      (bn0 output, transposed)
//   rT    [D2][64]        @ 12800  (gathered relation rows)
//   taP   [L][64]         @ 25600  (2a, b-permuted: bp=(b&15)*4+(b>>4))
//   wP    [L][64]         @ 29696  (w*exp2(-a^2), b-permuted)
//   sl    [L]             @ 33792
//   x2Bh  bf16[64][256]   @ 33856  (bn1 out, b-major, K zero-padded, hi)
//   x2Bl  bf16[64][256]   @ 42048  (lo part)
//   y4    [ih][k][j][64]  @ 50240  (stage-1 partials, ih=0..3 i-quarters)
#define WS_XT    0
#define WS_RT    12800
#define WS_TAP   25600
#define WS_WP    29696
#define WS_SL    33792
#define WS_X2BH  33856
#define WS_X2BL  42048
#define WS_Y     50240

typedef short s8v __attribute__((ext_vector_type(8)));   // 8 bf16 (4 VGPRs)
typedef float f4v __attribute__((ext_vector_type(4)));   // MFMA acc

__device__ __forceinline__ unsigned short bf16_rne(float x) {
  unsigned b = __float_as_uint(x);
  unsigned r = b + 0x7FFFu + ((b >> 16) & 1u);
  return (unsigned short)(r >> 16);
}
__device__ __forceinline__ void split2(float x, unsigned short& h,
                                       unsigned short& l) {
  h = bf16_rne(x);
  float hf = __uint_as_float(((unsigned)h) << 16);
  l = bf16_rne(x - hf);
}

// ---------------------------------------------------------------------------
// Kernel A: gathers + bn0 + literal pre-transforms + x2B zero-init. 4 blocks.
// ---------------------------------------------------------------------------
__global__ __launch_bounds__(256) void prep_kernel(
    const int* __restrict__ e1_idx, const int* __restrict__ r_idx,
    const float* __restrict__ E, const float* __restrict__ R,
    const float* __restrict__ lits, const float* __restrict__ c,
    const float* __restrict__ var_l, const float* __restrict__ nf,
    const float* __restrict__ bn0g, const float* __restrict__ bn0b,
    float* __restrict__ ws) {
  float* xT  = ws + WS_XT;
  float* rT  = ws + WS_RT;
  float* taP = ws + WS_TAP;
  float* wP  = ws + WS_WP;
  float* sl  = ws + WS_SL;
  int tid = threadIdx.x;

  if (blockIdx.x == 0) {
    if (tid < D1C) {
      int j = tid;
      float ev[64];
      float sum = 0.f, sq = 0.f;
#pragma unroll
      for (int b = 0; b < BB; b++) {
        float e = E[e1_idx[b] * D1C + j];
        ev[b] = e;
        sum += e; sq += e * e;
      }
      float mean = sum * (1.f / 64.f);
      float var  = sq  * (1.f / 64.f) - mean * mean;
      float inv  = __builtin_amdgcn_rsqf(var + BN_EPS);
      float g    = bn0g[j] * inv;
      float be   = bn0b[j] - mean * g;
#pragma unroll
      for (int b = 0; b < BB; b++) {
        xT[j * 64 + b] = g * ev[b] + be;
      }
    }
  } else if (blockIdx.x == 1) {
    for (int idx = tid; idx < D2C * 64; idx += 256) {
      int k = idx >> 6, b = idx & 63;
      rT[idx] = R[r_idx[b] * D2C + k];
    }
  } else if (blockIdx.x == 2) {
    // w*exp2(-(a-L)^2) = [w*exp2(-a^2)] * exp2(fma(2a, L, -L^2))
    // stored with b-permutation bp = (b&15)*4 + (b>>4) to match MFMA C-layout
    for (int idx = tid; idx < LLC * 64; idx += 256) {
      int l = idx >> 6, b = idx & 63;
      float s = sqrtf(LOG2E / var_l[l]);
      float a = (lits[e1_idx[b] * LLC + l] - c[l]) * s;
      int bp = (b & 15) * 4 + (b >> 4);
      taP[l * 64 + bp] = a + a;
      wP[l * 64 + bp]  = nf[r_idx[b] * LLC + l] * __builtin_amdgcn_exp2f(-a * a);
    }
    if (tid < LLC) sl[tid] = sqrtf(LOG2E / var_l[tid]);
  } else {
    // zero x2Bh/x2Bl (covers K padding 200..255)
    unsigned* z = (unsigned*)(ws + WS_X2BH);
    for (int i = tid; i < 16384; i += 256) z[i] = 0u;
  }
}

// ---------------------------------------------------------------------------
// Stage 1 v5: i-split x4 for occupancy. v4's measured failure: grid 200
// (< 256 CUs) -> 2 waves/SIMD, VALUBusy 12.7%, serial load->FMA chain fully
// exposed. Total j x b threads are FIXED (1600 waves), so the only route to
// more waves is splitting the i-reduction: grid (200 k, 4 ih), each block
// does 50 i -> 800 blocks = 25 waves/CU (6.25/SIMD), whole grid resident.
// No LDS, no barriers; lane-parallel float4 W/x loads straight from
// global (W read exactly once chip-wide); 1-deep explicit prefetch.
// Partials to y4[ih][k][j][64] (41 MB in ws); reduce sums 800 slices.
// ---------------------------------------------------------------------------
__global__ __launch_bounds__(512, 6) void stage1_kernel(
    const float* __restrict__ W, const float* __restrict__ ws_in,
    float* __restrict__ y) {
  const float* xT = ws_in + WS_XT;   // [i][64]
  const float* rT = ws_in + WS_RT;   // [k][64]

  int k = blockIdx.x;
  int ih = blockIdx.y;               // i-quarter
  int tid = threadIdx.x;
  int lane = tid & 63;
  int w = __builtin_amdgcn_readfirstlane(tid >> 6);
  int jc = w & 3, bh = w >> 2;
  int j4 = lane & 15, bq = lane >> 4;
  int j0 = jc * 64 + j4 * 4;         // 4 j's: j0..j0+3 (pad beyond 200)
  int b0 = bh * 32 + bq * 8;         // 8 b's
  bool jok = j0 < 200;               // waves 3,7: only j4<2 live
  int joff = jok ? j0 : 0;           // clamp W addr for dead lanes
  const float* Wk = W + k * 40000 + ih * 50 * 200 + joff;
  const float* xp = xT + ih * 50 * 64 + b0;

  float acc[4][8];
#pragma unroll
  for (int jj = 0; jj < 4; jj++)
#pragma unroll
    for (int bb = 0; bb < 8; bb++) acc[jj][bb] = 0.f;

  // 1-deep software pipeline: next i's loads issue before current i's FMAs
  float4 wv  = *(const float4*)(Wk);
  float4 xa  = *(const float4*)(xp);
  float4 xb2 = *(const float4*)(xp + 4);
#pragma unroll 5
  for (int i = 0; i < 50; i++) {
    float4 wv_n, xa_n, xb_n;
    if (i < 49) {
      wv_n = *(const float4*)(Wk + (i + 1) * 200);
      xa_n = *(const float4*)(xp + (i + 1) * 64);
      xb_n = *(const float4*)(xp + (i + 1) * 64 + 4);
    }
    float wc[4] = {wv.x, wv.y, wv.z, wv.w};
    float xv[8] = {xa.x, xa.y, xa.z, xa.w, xb2.x, xb2.y, xb2.z, xb2.w};
#pragma unroll
    for (int jj = 0; jj < 4; jj++)
#pragma unroll
      for (int bb = 0; bb < 8; bb++)
        acc[jj][bb] += wc[jj] * xv[bb];
    wv = wv_n; xa = xa_n; xb2 = xb_n;
  }

  if (jok) {
    float4 r0 = *(const float4*)(rT + k * 64 + b0);
    float4 r1 = *(const float4*)(rT + k * 64 + b0 + 4);
    float rv[8] = {r0.x, r0.y, r0.z, r0.w, r1.x, r1.y, r1.z, r1.w};
#pragma unroll
    for (int jj = 0; jj < 4; jj++) {
      float* yo = y + (((ih * 200 + k) * D1C) + j0 + jj) * 64 + b0;
      float4 o0 = make_float4(acc[jj][0] * rv[0], acc[jj][1] * rv[1],
                              acc[jj][2] * rv[2], acc[jj][3] * rv[3]);
      float4 o1 = make_float4(acc[jj][4] * rv[4], acc[jj][5] * rv[5],
                              acc[jj][6] * rv[6], acc[jj][7] * rv[7]);
      *(float4*)(yo) = o0;
      *(float4*)(yo + 4) = o1;
    }
  }
}

// ---------------------------------------------------------------------------
// Kernel C v2: reduce y4 over 800 (ih,k) slices, bn1 over b -> split-bf16
// x2B. 512 thr: kq = tid>>6 (0..7) each sums 100 slices; 8-way LDS fold.
// ---------------------------------------------------------------------------
__global__ __launch_bounds__(512) void reduce_bn1_kernel(
    const float* __restrict__ y, const float* __restrict__ bn1g,
    const float* __restrict__ bn1b, float* __restrict__ ws) {
  int j = blockIdx.x;
  int tid = threadIdx.x, b = tid & 63, kq = tid >> 6;

  float s = 0.f;
  const float* yp = y + ((kq * 100) * D1C + j) * 64 + b;
#pragma unroll 10
  for (int k = 0; k < 100; k++) s += yp[k * D1C * 64];

  __shared__ float part[512];
  part[tid] = s;
  __syncthreads();
  if (tid < 64) {
    float v = part[tid]       + part[64 + tid]  + part[128 + tid] +
              part[192 + tid] + part[256 + tid] + part[320 + tid] +
              part[384 + tid] + part[448 + tid];
    float sum = v, sq = v * v;
#pragma unroll
    for (int o = 32; o > 0; o >>= 1) {
      sum += __shfl_xor(sum, o, 64);
      sq  += __shfl_xor(sq,  o, 64);
    }
    float mean = sum * (1.f / 64.f);
    float var  = sq  * (1.f / 64.f) - mean * mean;
    float inv  = __builtin_amdgcn_rsqf(var + BN_EPS);
    float g    = bn1g[j] * inv;
    float be   = bn1b[j] - mean * g;
    float xv   = g * v + be;
    unsigned short h, l;
    split2(xv, h, l);
    unsigned short* xh = (unsigned short*)(ws + WS_X2BH);
    unsigned short* xl = (unsigned short*)(ws + WS_X2BL);
    xh[b * 256 + j] = h;
    xl[b * 256 + j] = l;
  }
}

// ---------------------------------------------------------------------------
// Final (R6 version, measured-best 47.1 us; pinned after 5 failed
// restructures R2/R3/R4/R5/R7 — occupancy is NOT its limiter): score_l via
// split-bf16 MFMA 16x16x32; score_n via R8 loop on the C-fragment mapping.
// grid 625, 256 thr = 4 waves.
// ---------------------------------------------------------------------------
__global__ __launch_bounds__(256, 4) void final_kernel(
    const float* __restrict__ E, const float* __restrict__ lits,
    const float* __restrict__ ws, float* __restrict__ out) {
  const float* taP = ws + WS_TAP;
  const float* wP  = ws + WS_WP;
  const float* sl  = ws + WS_SL;
  const unsigned short* x2bh = (const unsigned short*)(ws + WS_X2BH);
  const unsigned short* x2bl = (const unsigned short*)(ws + WS_X2BL);

  __shared__ float SM[9216];                 // 36864 B arena
  unsigned short* Ah = (unsigned short*)SM;  // [64][72] bf16
  unsigned short* Al = Ah + 4608;
  unsigned short* Bh = Ah + 9216;
  unsigned short* Bl = Ah + 13824;

  int n0 = blockIdx.x * 64;
  int tid = threadIdx.x;
  int lane = tid & 63;
  int w = __builtin_amdgcn_readfirstlane(tid >> 6);
  int ln = lane & 15;
  int quad = lane >> 4;

  f4v acc[4];
#pragma unroll
  for (int t = 0; t < 4; t++) acc[t] = (f4v){0.f, 0.f, 0.f, 0.f};

  // ---- score_l: 4 K-slabs of 64 ----
  for (int q = 0; q < 4; q++) {
    int k0 = q * 64;
    __syncthreads();
    // stage E slab -> Ah/Al (split-bf16 on the fly)
#pragma unroll
    for (int it = 0; it < 4; it++) {
      int idx = tid + it * 256;
      int row = idx >> 4, c4 = idx & 15, cc = c4 * 4;
      float4 v = make_float4(0.f, 0.f, 0.f, 0.f);
      if (k0 + cc < 200) v = *(const float4*)(E + (n0 + row) * D1C + k0 + cc);
      unsigned short h0, l0, h1, l1, h2, l2, h3, l3;
      split2(v.x, h0, l0); split2(v.y, h1, l1);
      split2(v.z, h2, l2); split2(v.w, h3, l3);
      *(ushort4*)(Ah + row * 72 + cc) = make_ushort4(h0, h1, h2, h3);
      *(ushort4*)(Al + row * 72 + cc) = make_ushort4(l0, l1, l2, l3);
    }
    // stage x2B slab -> Bh/Bl (straight copy; K-pad already zeroed)
#pragma unroll
    for (int it = 0; it < 4; it++) {
      int idx = tid + it * 256;
      int row = idx >> 4, c4 = idx & 15;
      *(ushort4*)(Bh + row * 72 + c4 * 4) =
          *(const ushort4*)(x2bh + row * 256 + k0 + c4 * 4);
      *(ushort4*)(Bl + row * 72 + c4 * 4) =
          *(const ushort4*)(x2bl + row * 256 + k0 + c4 * 4);
    }
    __syncthreads();

    const unsigned short* Ab  = Ah + (16 * w + ln) * 72 + quad * 8;
    const unsigned short* Alb = Al + (16 * w + ln) * 72 + quad * 8;
#pragma unroll
    for (int ks = 0; ks < 64; ks += 32) {
      s8v ah = *(const s8v*)(Ab + ks);
      s8v al = *(const s8v*)(Alb + ks);
#pragma unroll
      for (int t = 0; t < 4; t++) {
        s8v bh = *(const s8v*)(Bh + (16 * t + ln) * 72 + quad * 8 + ks);
        s8v bl = *(const s8v*)(Bl + (16 * t + ln) * 72 + quad * 8 + ks);
        acc[t] = __builtin_amdgcn_mfma_f32_16x16x32_bf16(ah, bh, acc[t], 0, 0, 0);
        acc[t] = __builtin_amdgcn_mfma_f32_16x16x32_bf16(al, bh, acc[t], 0, 0, 0);
        acc[t] = __builtin_amdgcn_mfma_f32_16x16x32_bf16(ah, bl, acc[t], 0, 0, 0);
      }
    }
  }

  // ---- phase B: score_n on the C-fragment mapping ----
  float* Llds = SM;           // [64][68] scaled lits, rows=l, cols=n-local
  float* TAl  = SM + 4352;    // [32][64] ta half (b-permuted)
  float* Wl   = SM + 6400;    // [32][64]
  int nlb = 16 * w + 4 * quad;

  __syncthreads();
#pragma unroll
  for (int it = 0; it < 4; it++) {
    int idx = tid + it * 256;
    int row = idx >> 4, c4 = idx & 15;
    float4 v = *(const float4*)(lits + (n0 + row) * LLC + c4 * 4);
    int l = c4 * 4;
    Llds[(l + 0) * 68 + row] = v.x * sl[l + 0];
    Llds[(l + 1) * 68 + row] = v.y * sl[l + 1];
    Llds[(l + 2) * 68 + row] = v.z * sl[l + 2];
    Llds[(l + 3) * 68 + row] = v.w * sl[l + 3];
  }

  for (int h = 0; h < 2; h++) {
    __syncthreads();          // h=0: Llds staged; h=1: previous reads done
#pragma unroll
    for (int it = 0; it < 2; it++) {
      int idx = tid + it * 256;
      ((float4*)TAl)[idx] = ((const float4*)(taP + h * 2048))[idx];
      ((float4*)Wl)[idx]  = ((const float4*)(wP  + h * 2048))[idx];
    }
    __syncthreads();
    for (int ll = 0; ll < 32; ll++) {
      float4 Lv = *(const float4*)(Llds + (h * 32 + ll) * 68 + nlb);
      float4 ta = *(const float4*)(TAl + ll * 64 + 4 * ln);
      float4 wv = *(const float4*)(Wl  + ll * 64 + 4 * ln);
      float Lc[4]  = {Lv.x, Lv.y, Lv.z, Lv.w};
      float tac[4] = {ta.x, ta.y, ta.z, ta.w};
      float wvc[4] = {wv.x, wv.y, wv.z, wv.w};
      float n2[4];
#pragma unroll
      for (int r = 0; r < 4; r++) n2[r] = -Lc[r] * Lc[r];
#pragma unroll
      for (int t = 0; t < 4; t++) {
#pragma unroll
        for (int r = 0; r < 4; r++) {
          acc[t][r] += wvc[t] *
              __builtin_amdgcn_exp2f(__builtin_fmaf(tac[t], Lc[r], n2[r]));
        }
      }
    }
  }

  // ---- sigmoid + float4 stores (4 consecutive n per b-row) ----
#pragma unroll
  for (int t = 0; t < 4; t++) {
    float4 o;
    o.x = __builtin_amdgcn_rcpf(1.f + __builtin_amdgcn_exp2f(-LOG2E * acc[t][0]));
    o.y = __builtin_amdgcn_rcpf(1.f + __builtin_amdgcn_exp2f(-LOG2E * acc[t][1]));
    o.z = __builtin_amdgcn_rcpf(1.f + __builtin_amdgcn_exp2f(-LOG2E * acc[t][2]));
    o.w = __builtin_amdgcn_rcpf(1.f + __builtin_amdgcn_exp2f(-LOG2E * acc[t][3]));
    *(float4*)(out + (size_t)(16 * t + ln) * NEC + n0 + nlb) = o;
  }
}

// ---------------------------------------------------------------------------
extern "C" void kernel_launch(void* const* d_in, const int* in_sizes, int n_in,
                              void* d_out, int out_size, void* d_ws, size_t ws_size,
                              hipStream_t stream) {
  (void)in_sizes; (void)n_in; (void)out_size; (void)ws_size;
  const int*   e1    = (const int*)d_in[0];
  const int*   ri    = (const int*)d_in[1];
  const float* E     = (const float*)d_in[2];
  const float* R     = (const float*)d_in[3];
  const float* W     = (const float*)d_in[4];
  const float* lits  = (const float*)d_in[5];
  const float* c     = (const float*)d_in[6];
  const float* var_l = (const float*)d_in[7];
  const float* nf    = (const float*)d_in[8];
  const float* bn0g  = (const float*)d_in[9];
  const float* bn0b  = (const float*)d_in[10];
  const float* bn1g  = (const float*)d_in[11];
  const float* bn1b  = (const float*)d_in[12];
  float* out = (float*)d_out;
  float* ws  = (float*)d_ws;
  float* y   = ws + WS_Y;

  prep_kernel<<<4, 256, 0, stream>>>(e1, ri, E, R, lits, c, var_l, nf,
                                     bn0g, bn0b, ws);
  stage1_kernel<<<dim3(200, 4), 512, 0, stream>>>(W, ws, y);
  reduce_bn1_kernel<<<200, 512, 0, stream>>>(y, bn1g, bn1b, ws);
  final_kernel<<<625, 256, 0, stream>>>(E, lits, ws, out);
}

// Round 12
// 187.694 us; speedup vs baseline: 1.4648x; 1.4648x over previous
//
#include <hip/hip_runtime.h>
#include <math.h>

// Problem constants
#define BB    64
#define NEC   40000
#define NRC   500
#define D1C   200
#define D2C   200
#define LLC   64
#define BN_EPS 1e-5f
#define LOG2E 1.4426950408889634f

// ws layout (floats):
//   xT    [D1][64]        @ 0      (bn0 output, transposed)
//   rT    [D2][64]        @ 12800  (gathered relation rows)
//   taP   [L][64]         @ 25600  (2a, b-permuted: bp=(b&15)*4+(b>>4))
//   wP    [L][64]         @ 29696  (w*exp2(-a^2), b-permuted)
//   sl    [L]             @ 33792
//   x2Bh  bf16[64][256]   @ 33856  (bn1 out, b-major, K zero-padded, hi)
//   x2Bl  bf16[64][256]   @ 42048  (lo part)
//   y     [k][j][64]      @ 50240  (stage-1 partials)
#define WS_XT    0
#define WS_RT    12800
#define WS_TAP   25600
#define WS_WP    29696
#define WS_SL    33792
#define WS_X2BH  33856
#define WS_X2BL  42048
#define WS_Y     50240

typedef short s8v __attribute__((ext_vector_type(8)));   // 8 bf16 (4 VGPRs)
typedef float f4v __attribute__((ext_vector_type(4)));   // MFMA acc

__device__ __forceinline__ unsigned short bf16_rne(float x) {
  unsigned b = __float_as_uint(x);
  unsigned r = b + 0x7FFFu + ((b >> 16) & 1u);
  return (unsigned short)(r >> 16);
}
__device__ __forceinline__ void split2(float x, unsigned short& h,
                                       unsigned short& l) {
  h = bf16_rne(x);
  float hf = __uint_as_float(((unsigned)h) << 16);
  l = bf16_rne(x - hf);
}

typedef __attribute__((address_space(1))) const void gvoid_t;
typedef __attribute__((address_space(3))) void lvoid_t;
__device__ __forceinline__ void gload_lds16(const float* g, float* l) {
  __builtin_amdgcn_global_load_lds((gvoid_t*)g, (lvoid_t*)l, 16, 0, 0);
}

// ---------------------------------------------------------------------------
// Kernel A v4: same work as the proven prep, spread over 16 blocks instead
// of 4 (the gathers are independent elementwise loops; only bn0 needs
// cross-b stats and keeps one block). 4x-8x more CUs on the latency-bound
// scattered gathers.
//   block 0      : bn0 (register-cached gather, R9 version)
//   blocks 1-4   : rT gather, 4-way split
//   blocks 5-12  : taP/wP transform, 8-way split (+ sl on block 5)
//   blocks 13-15 : x2B zero, 3-way strided
// ---------------------------------------------------------------------------
__global__ __launch_bounds__(256) void prep_kernel(
    const int* __restrict__ e1_idx, const int* __restrict__ r_idx,
    const float* __restrict__ E, const float* __restrict__ R,
    const float* __restrict__ lits, const float* __restrict__ c,
    const float* __restrict__ var_l, const float* __restrict__ nf,
    const float* __restrict__ bn0g, const float* __restrict__ bn0b,
    float* __restrict__ ws) {
  float* xT  = ws + WS_XT;
  float* rT  = ws + WS_RT;
  float* taP = ws + WS_TAP;
  float* wP  = ws + WS_WP;
  float* sl  = ws + WS_SL;
  int tid = threadIdx.x;
  int bid = blockIdx.x;

  if (bid == 0) {
    if (tid < D1C) {
      int j = tid;
      float ev[64];
      float sum = 0.f, sq = 0.f;
#pragma unroll
      for (int b = 0; b < BB; b++) {
        float e = E[e1_idx[b] * D1C + j];
        ev[b] = e;
        sum += e; sq += e * e;
      }
      float mean = sum * (1.f / 64.f);
      float var  = sq  * (1.f / 64.f) - mean * mean;
      float inv  = __builtin_amdgcn_rsqf(var + BN_EPS);
      float g    = bn0g[j] * inv;
      float be   = bn0b[j] - mean * g;
#pragma unroll
      for (int b = 0; b < BB; b++) {
        xT[j * 64 + b] = g * ev[b] + be;
      }
    }
  } else if (bid <= 4) {
    int part = bid - 1;                      // 0..3, 3200 elems each
    int end = part * 3200 + 3200;
    for (int idx = part * 3200 + tid; idx < end; idx += 256) {
      int k = idx >> 6, b = idx & 63;
      rT[idx] = R[r_idx[b] * D2C + k];
    }
  } else if (bid <= 12) {
    // w*exp2(-(a-L)^2) = [w*exp2(-a^2)] * exp2(fma(2a, L, -L^2))
    // stored with b-permutation bp = (b&15)*4 + (b>>4) to match MFMA C-layout
    int part = bid - 5;                      // 0..7, 512 elems each
#pragma unroll
    for (int it = 0; it < 2; it++) {
      int idx = part * 512 + it * 256 + tid;
      int b = idx >> 6, l = idx & 63;
      float s = sqrtf(LOG2E / var_l[l]);
      float a = (lits[e1_idx[b] * LLC + l] - c[l]) * s;
      int bp = (b & 15) * 4 + (b >> 4);
      taP[l * 64 + bp] = a + a;
      wP[l * 64 + bp]  = nf[r_idx[b] * LLC + l] * __builtin_amdgcn_exp2f(-a * a);
    }
    if (bid == 5 && tid < LLC) sl[tid] = sqrtf(LOG2E / var_l[tid]);
  } else {
    // zero x2Bh/x2Bl (covers K padding 200..255), 3 blocks strided
    unsigned* z = (unsigned*)(ws + WS_X2BH);
    for (int i = (bid - 13) * 256 + tid; i < 16384; i += 768) z[i] = 0u;
  }
}

// ---------------------------------------------------------------------------
// Stage 1 v3 (REVERTED, proven 49 us — best of 5 designs): lane-parallel W
// via double-buffered LDS slabs + xT in LDS. global_load_lds issues 8
// fire-and-forget loads/wave with no VGPR dependency (why it beats the
// global-direct v4/v5: their load->FMA register chains serialize on HBM
// latency at low waves/SIMD). ds_reads dual-issue under the 32-FMA bursts.
// ---------------------------------------------------------------------------
#define S1_STAGE(buf_, s_) do {                                         \
    int gbase_ = kbase + (s_) * 8000;                                   \
    _Pragma("unroll")                                                   \
    for (int r_ = 0; r_ < 4; r_++) {                                    \
      int off_ = r_ * 2048 + w * 256;                                   \
      int gi_ = gbase_ + off_ + lane4;                                  \
      gi_ = gi_ < 7999996 ? gi_ : 7999996;                              \
      gload_lds16(W + gi_, &Wb[buf_][off_]);                            \
    }                                                                   \
  } while (0)

__global__ __launch_bounds__(512) void stage1_kernel(
    const float* __restrict__ W, const float* __restrict__ ws_in,
    float* __restrict__ y) {
  const float* xTg = ws_in + WS_XT;  // [i][64] (global)
  const float* rT  = ws_in + WS_RT;  // [k][64]
  __shared__ float Wb[2][8192];      // 64 KB: 2 x (40 rows x 200 + pad)
  __shared__ float xTl[12800];       // 51.2 KB: full xT

  int k = blockIdx.x;
  int tid = threadIdx.x;
  int lane = tid & 63;
  int w = __builtin_amdgcn_readfirstlane(tid >> 6);
  int jc = w & 3, bh = w >> 2;
  int j4 = lane & 15, bq = lane >> 4;
  int j0 = jc * 64 + j4 * 4;         // 4 j's: j0..j0+3 (pad beyond 200)
  int b0 = bh * 32 + bq * 8;         // 8 b's
  bool jok = j0 < 200;               // waves 3,7: only j4<2 live
  int joff = jok ? j0 : 0;           // clamp LDS read addr for dead lanes
  int kbase = k * 40000;
  int lane4 = lane * 4;

  // stage full xT -> LDS: 12800 floats = 50 wave-chunks of 256 floats
  for (int cc = w; cc < 50; cc += 8) {
    gload_lds16(xTg + cc * 256 + lane4, &xTl[cc * 256]);
  }
  S1_STAGE(0, 0);

  float acc[4][8];
#pragma unroll
  for (int jj = 0; jj < 4; jj++)
#pragma unroll
    for (int bb = 0; bb < 8; bb++) acc[jj][bb] = 0.f;

  for (int s = 0; s < 5; s++) {
    __syncthreads();                 // drains vmcnt -> slab s (and xT) ready
    if (s < 4) S1_STAGE((s + 1) & 1, s + 1);   // prefetch under compute
    const float* Ws = Wb[s & 1];
    const float* xrow = xTl + s * 40 * 64 + b0;
#pragma unroll 8
    for (int ri = 0; ri < 40; ri++) {
      float4 wv  = *(const float4*)(Ws + ri * 200 + joff);
      float4 xa  = *(const float4*)(xrow + ri * 64);
      float4 xb2 = *(const float4*)(xrow + ri * 64 + 4);
      float wc[4] = {wv.x, wv.y, wv.z, wv.w};
      float xv[8] = {xa.x, xa.y, xa.z, xa.w, xb2.x, xb2.y, xb2.z, xb2.w};
#pragma unroll
      for (int jj = 0; jj < 4; jj++)
#pragma unroll
        for (int bb = 0; bb < 8; bb++)
          acc[jj][bb] += wc[jj] * xv[bb];
    }
  }

  if (jok) {
    float4 r0 = *(const float4*)(rT + k * 64 + b0);
    float4 r1 = *(const float4*)(rT + k * 64 + b0 + 4);
    float rv[8] = {r0.x, r0.y, r0.z, r0.w, r1.x, r1.y, r1.z, r1.w};
#pragma unroll
    for (int jj = 0; jj < 4; jj++) {
      float* yo = y + (k * D1C + j0 + jj) * 64 + b0;
      float4 o0 = make_float4(acc[jj][0] * rv[0], acc[jj][1] * rv[1],
                              acc[jj][2] * rv[2], acc[jj][3] * rv[3]);
      float4 o1 = make_float4(acc[jj][4] * rv[4], acc[jj][5] * rv[5],
                              acc[jj][6] * rv[6], acc[jj][7] * rv[7]);
      *(float4*)(yo) = o0;
      *(float4*)(yo + 4) = o1;
    }
  }
}

// ---------------------------------------------------------------------------
// Kernel C: reduce y over k, bn1 over b -> split-bf16 x2B (b-major, K-padded)
// (R6/R9 proven version)
// ---------------------------------------------------------------------------
__global__ __launch_bounds__(256) void reduce_bn1_kernel(
    const float* __restrict__ y, const float* __restrict__ bn1g,
    const float* __restrict__ bn1b, float* __restrict__ ws) {
  int j = blockIdx.x;
  int tid = threadIdx.x, b = tid & 63, kq = tid >> 6;

  float s = 0.f;
  const float* yp = y + (kq * 50 * D1C + j) * 64 + b;
#pragma unroll 10
  for (int k = 0; k < 50; k++) s += yp[k * D1C * 64];

  __shared__ float part[256];
  part[tid] = s;
  __syncthreads();
  if (tid < 64) {
    float v = part[tid] + part[64 + tid] + part[128 + tid] + part[192 + tid];
    float sum = v, sq = v * v;
#pragma unroll
    for (int o = 32; o > 0; o >>= 1) {
      sum += __shfl_xor(sum, o, 64);
      sq  += __shfl_xor(sq,  o, 64);
    }
    float mean = sum * (1.f / 64.f);
    float var  = sq  * (1.f / 64.f) - mean * mean;
    float inv  = __builtin_amdgcn_rsqf(var + BN_EPS);
    float g    = bn1g[j] * inv;
    float be   = bn1b[j] - mean * g;
    float xv   = g * v + be;
    unsigned short h, l;
    split2(xv, h, l);
    unsigned short* xh = (unsigned short*)(ws + WS_X2BH);
    unsigned short* xl = (unsigned short*)(ws + WS_X2BL);
    xh[tid * 256 + j] = h;
    xl[tid * 256 + j] = l;
  }
}

// ---------------------------------------------------------------------------
// Final (R6 version, measured-best 47.1 us; pinned after 5 failed
// restructures R2/R3/R4/R5/R7 — occupancy is NOT its limiter): score_l via
// split-bf16 MFMA 16x16x32; score_n via R8 loop on the C-fragment mapping.
// grid 625, 256 thr = 4 waves.
// ---------------------------------------------------------------------------
__global__ __launch_bounds__(256, 4) void final_kernel(
    const float* __restrict__ E, const float* __restrict__ lits,
    const float* __restrict__ ws, float* __restrict__ out) {
  const float* taP = ws + WS_TAP;
  const float* wP  = ws + WS_WP;
  const float* sl  = ws + WS_SL;
  const unsigned short* x2bh = (const unsigned short*)(ws + WS_X2BH);
  const unsigned short* x2bl = (const unsigned short*)(ws + WS_X2BL);

  __shared__ float SM[9216];                 // 36864 B arena
  unsigned short* Ah = (unsigned short*)SM;  // [64][72] bf16
  unsigned short* Al = Ah + 4608;
  unsigned short* Bh = Ah + 9216;
  unsigned short* Bl = Ah + 13824;

  int n0 = blockIdx.x * 64;
  int tid = threadIdx.x;
  int lane = tid & 63;
  int w = __builtin_amdgcn_readfirstlane(tid >> 6);
  int ln = lane & 15;
  int quad = lane >> 4;

  f4v acc[4];
#pragma unroll
  for (int t = 0; t < 4; t++) acc[t] = (f4v){0.f, 0.f, 0.f, 0.f};

  // ---- score_l: 4 K-slabs of 64 ----
  for (int q = 0; q < 4; q++) {
    int k0 = q * 64;
    __syncthreads();
    // stage E slab -> Ah/Al (split-bf16 on the fly)
#pragma unroll
    for (int it = 0; it < 4; it++) {
      int idx = tid + it * 256;
      int row = idx >> 4, c4 = idx & 15, cc = c4 * 4;
      float4 v = make_float4(0.f, 0.f, 0.f, 0.f);
      if (k0 + cc < 200) v = *(const float4*)(E + (n0 + row) * D1C + k0 + cc);
      unsigned short h0, l0, h1, l1, h2, l2, h3, l3;
      split2(v.x, h0, l0); split2(v.y, h1, l1);
      split2(v.z, h2, l2); split2(v.w, h3, l3);
      *(ushort4*)(Ah + row * 72 + cc) = make_ushort4(h0, h1, h2, h3);
      *(ushort4*)(Al + row * 72 + cc) = make_ushort4(l0, l1, l2, l3);
    }
    // stage x2B slab -> Bh/Bl (straight copy; K-pad already zeroed)
#pragma unroll
    for (int it = 0; it < 4; it++) {
      int idx = tid + it * 256;
      int row = idx >> 4, c4 = idx & 15;
      *(ushort4*)(Bh + row * 72 + c4 * 4) =
          *(const ushort4*)(x2bh + row * 256 + k0 + c4 * 4);
      *(ushort4*)(Bl + row * 72 + c4 * 4) =
          *(const ushort4*)(x2bl + row * 256 + k0 + c4 * 4);
    }
    __syncthreads();

    const unsigned short* Ab  = Ah + (16 * w + ln) * 72 + quad * 8;
    const unsigned short* Alb = Al + (16 * w + ln) * 72 + quad * 8;
#pragma unroll
    for (int ks = 0; ks < 64; ks += 32) {
      s8v ah = *(const s8v*)(Ab + ks);
      s8v al = *(const s8v*)(Alb + ks);
#pragma unroll
      for (int t = 0; t < 4; t++) {
        s8v bh = *(const s8v*)(Bh + (16 * t + ln) * 72 + quad * 8 + ks);
        s8v bl = *(const s8v*)(Bl + (16 * t + ln) * 72 + quad * 8 + ks);
        acc[t] = __builtin_amdgcn_mfma_f32_16x16x32_bf16(ah, bh, acc[t], 0, 0, 0);
        acc[t] = __builtin_amdgcn_mfma_f32_16x16x32_bf16(al, bh, acc[t], 0, 0, 0);
        acc[t] = __builtin_amdgcn_mfma_f32_16x16x32_bf16(ah, bl, acc[t], 0, 0, 0);
      }
    }
  }

  // ---- phase B: score_n on the C-fragment mapping ----
  float* Llds = SM;           // [64][68] scaled lits, rows=l, cols=n-local
  float* TAl  = SM + 4352;    // [32][64] ta half (b-permuted)
  float* Wl   = SM + 6400;    // [32][64]
  int nlb = 16 * w + 4 * quad;

  __syncthreads();
#pragma unroll
  for (int it = 0; it < 4; it++) {
    int idx = tid + it * 256;
    int row = idx >> 4, c4 = idx & 15;
    float4 v = *(const float4*)(lits + (n0 + row) * LLC + c4 * 4);
    int l = c4 * 4;
    Llds[(l + 0) * 68 + row] = v.x * sl[l + 0];
    Llds[(l + 1) * 68 + row] = v.y * sl[l + 1];
    Llds[(l + 2) * 68 + row] = v.z * sl[l + 2];
    Llds[(l + 3) * 68 + row] = v.w * sl[l + 3];
  }

  for (int h = 0; h < 2; h++) {
    __syncthreads();          // h=0: Llds staged; h=1: previous reads done
#pragma unroll
    for (int it = 0; it < 2; it++) {
      int idx = tid + it * 256;
      ((float4*)TAl)[idx] = ((const float4*)(taP + h * 2048))[idx];
      ((float4*)Wl)[idx]  = ((const float4*)(wP  + h * 2048))[idx];
    }
    __syncthreads();
    for (int ll = 0; ll < 32; ll++) {
      float4 Lv = *(const float4*)(Llds + (h * 32 + ll) * 68 + nlb);
      float4 ta = *(const float4*)(TAl + ll * 64 + 4 * ln);
      float4 wv = *(const float4*)(Wl  + ll * 64 + 4 * ln);
      float Lc[4]  = {Lv.x, Lv.y, Lv.z, Lv.w};
      float tac[4] = {ta.x, ta.y, ta.z, ta.w};
      float wvc[4] = {wv.x, wv.y, wv.z, wv.w};
      float n2[4];
#pragma unroll
      for (int r = 0; r < 4; r++) n2[r] = -Lc[r] * Lc[r];
#pragma unroll
      for (int t = 0; t < 4; t++) {
#pragma unroll
        for (int r = 0; r < 4; r++) {
          acc[t][r] += wvc[t] *
              __builtin_amdgcn_exp2f(__builtin_fmaf(tac[t], Lc[r], n2[r]));
        }
      }
    }
  }

  // ---- sigmoid + float4 stores (4 consecutive n per b-row) ----
#pragma unroll
  for (int t = 0; t < 4; t++) {
    float4 o;
    o.x = __builtin_amdgcn_rcpf(1.f + __builtin_amdgcn_exp2f(-LOG2E * acc[t][0]));
    o.y = __builtin_amdgcn_rcpf(1.f + __builtin_amdgcn_exp2f(-LOG2E * acc[t][1]));
    o.z = __builtin_amdgcn_rcpf(1.f + __builtin_amdgcn_exp2f(-LOG2E * acc[t][2]));
    o.w = __builtin_amdgcn_rcpf(1.f + __builtin_amdgcn_exp2f(-LOG2E * acc[t][3]));
    *(float4*)(out + (size_t)(16 * t + ln) * NEC + n0 + nlb) = o;
  }
}

// ---------------------------------------------------------------------------
extern "C" void kernel_launch(void* const* d_in, const int* in_sizes, int n_in,
                              void* d_out, int out_size, void* d_ws, size_t ws_size,
                              hipStream_t stream) {
  (void)in_sizes; (void)n_in; (void)out_size; (void)ws_size;
  const int*   e1    = (const int*)d_in[0];
  const int*   ri    = (const int*)d_in[1];
  const float* E     = (const float*)d_in[2];
  const float* R     = (const float*)d_in[3];
  const float* W     = (const float*)d_in[4];
  const float* lits  = (const float*)d_in[5];
  const float* c     = (const float*)d_in[6];
  const float* var_l = (const float*)d_in[7];
  const float* nf    = (const float*)d_in[8];
  const float* bn0g  = (const float*)d_in[9];
  const float* bn0b  = (const float*)d_in[10];
  const float* bn1g  = (const float*)d_in[11];
  const float* bn1b  = (const float*)d_in[12];
  float* out = (float*)d_out;
  float* ws  = (float*)d_ws;
  float* y   = ws + WS_Y;

  prep_kernel<<<16, 256, 0, stream>>>(e1, ri, E, R, lits, c, var_l, nf,
                                      bn0g, bn0b, ws);
  stage1_kernel<<<200, 512, 0, stream>>>(W, ws, y);
  reduce_bn1_kernel<<<200, 256, 0, stream>>>(y, bn1g, bn1b, ws);
  final_kernel<<<625, 256, 0, stream>>>(E, lits, ws, out);
}

// Round 13
// 185.861 us; speedup vs baseline: 1.4793x; 1.0099x over previous
//
#include <hip/hip_runtime.h>
#include <math.h>

// Problem constants
#define BB    64
#define NEC   40000
#define NRC   500
#define D1C   200
#define D2C   200
#define LLC   64
#define BN_EPS 1e-5f
#define LOG2E 1.4426950408889634f

// ws layout (floats):
//   xT    [D1][64]        @ 0      (bn0 output, transposed)
//   rT    [D2][64]        @ 12800  (gathered relation rows)
//   taP   [L][64]         @ 25600  (2a, b-permuted: bp=(b&15)*4+(b>>4))
//   wP    [L][64]         @ 29696  (w*exp2(-a^2), b-permuted)
//   sl    [L]             @ 33792
//   x2Bh  bf16[64][256]   @ 33856  (bn1 out, b-major, K zero-padded, hi)
//   x2Bl  bf16[64][256]   @ 42048  (lo part)
//   y     [j][k][64]      @ 50240  (stage-1 partials, j-major for streaming
//                                   reduce: block j reads one contiguous
//                                   51.2 KB span instead of 200 loads at
//                                   51.2 KB stride)
#define WS_XT    0
#define WS_RT    12800
#define WS_TAP   25600
#define WS_WP    29696
#define WS_SL    33792
#define WS_X2BH  33856
#define WS_X2BL  42048
#define WS_Y     50240

typedef short s8v __attribute__((ext_vector_type(8)));   // 8 bf16 (4 VGPRs)
typedef float f4v __attribute__((ext_vector_type(4)));   // MFMA acc

__device__ __forceinline__ unsigned short bf16_rne(float x) {
  unsigned b = __float_as_uint(x);
  unsigned r = b + 0x7FFFu + ((b >> 16) & 1u);
  return (unsigned short)(r >> 16);
}
__device__ __forceinline__ void split2(float x, unsigned short& h,
                                       unsigned short& l) {
  h = bf16_rne(x);
  float hf = __uint_as_float(((unsigned)h) << 16);
  l = bf16_rne(x - hf);
}

typedef __attribute__((address_space(1))) const void gvoid_t;
typedef __attribute__((address_space(3))) void lvoid_t;
__device__ __forceinline__ void gload_lds16(const float* g, float* l) {
  __builtin_amdgcn_global_load_lds((gvoid_t*)g, (lvoid_t*)l, 16, 0, 0);
}

// ---------------------------------------------------------------------------
// Kernel A v4 (R12, measured win): prep spread over 16 blocks.
//   block 0      : bn0 (register-cached gather)
//   blocks 1-4   : rT gather, 4-way split
//   blocks 5-12  : taP/wP transform, 8-way split (+ sl on block 5)
//   blocks 13-15 : x2B zero, 3-way strided
// ---------------------------------------------------------------------------
__global__ __launch_bounds__(256) void prep_kernel(
    const int* __restrict__ e1_idx, const int* __restrict__ r_idx,
    const float* __restrict__ E, const float* __restrict__ R,
    const float* __restrict__ lits, const float* __restrict__ c,
    const float* __restrict__ var_l, const float* __restrict__ nf,
    const float* __restrict__ bn0g, const float* __restrict__ bn0b,
    float* __restrict__ ws) {
  float* xT  = ws + WS_XT;
  float* rT  = ws + WS_RT;
  float* taP = ws + WS_TAP;
  float* wP  = ws + WS_WP;
  float* sl  = ws + WS_SL;
  int tid = threadIdx.x;
  int bid = blockIdx.x;

  if (bid == 0) {
    if (tid < D1C) {
      int j = tid;
      float ev[64];
      float sum = 0.f, sq = 0.f;
#pragma unroll
      for (int b = 0; b < BB; b++) {
        float e = E[e1_idx[b] * D1C + j];
        ev[b] = e;
        sum += e; sq += e * e;
      }
      float mean = sum * (1.f / 64.f);
      float var  = sq  * (1.f / 64.f) - mean * mean;
      float inv  = __builtin_amdgcn_rsqf(var + BN_EPS);
      float g    = bn0g[j] * inv;
      float be   = bn0b[j] - mean * g;
#pragma unroll
      for (int b = 0; b < BB; b++) {
        xT[j * 64 + b] = g * ev[b] + be;
      }
    }
  } else if (bid <= 4) {
    int part = bid - 1;                      // 0..3, 3200 elems each
    int end = part * 3200 + 3200;
    for (int idx = part * 3200 + tid; idx < end; idx += 256) {
      int k = idx >> 6, b = idx & 63;
      rT[idx] = R[r_idx[b] * D2C + k];
    }
  } else if (bid <= 12) {
    // w*exp2(-(a-L)^2) = [w*exp2(-a^2)] * exp2(fma(2a, L, -L^2))
    // stored with b-permutation bp = (b&15)*4 + (b>>4) to match MFMA C-layout
    int part = bid - 5;                      // 0..7, 512 elems each
#pragma unroll
    for (int it = 0; it < 2; it++) {
      int idx = part * 512 + it * 256 + tid;
      int b = idx >> 6, l = idx & 63;
      float s = sqrtf(LOG2E / var_l[l]);
      float a = (lits[e1_idx[b] * LLC + l] - c[l]) * s;
      int bp = (b & 15) * 4 + (b >> 4);
      taP[l * 64 + bp] = a + a;
      wP[l * 64 + bp]  = nf[r_idx[b] * LLC + l] * __builtin_amdgcn_exp2f(-a * a);
    }
    if (bid == 5 && tid < LLC) sl[tid] = sqrtf(LOG2E / var_l[tid]);
  } else {
    // zero x2Bh/x2Bl (covers K padding 200..255), 3 blocks strided
    unsigned* z = (unsigned*)(ws + WS_X2BH);
    for (int i = (bid - 13) * 256 + tid; i < 16384; i += 768) z[i] = 0u;
  }
}

// ---------------------------------------------------------------------------
// Stage 1 v3 (proven 49 us): lane-parallel W via double-buffered LDS slabs
// + xT in LDS. ONLY change vs R12: y written j-major ([j][k][64]) so the
// reduce can stream. Same store instruction count/pattern (stores are
// fire-and-forget; only inter-segment stride grows).
// ---------------------------------------------------------------------------
#define S1_STAGE(buf_, s_) do {                                         \
    int gbase_ = kbase + (s_) * 8000;                                   \
    _Pragma("unroll")                                                   \
    for (int r_ = 0; r_ < 4; r_++) {                                    \
      int off_ = r_ * 2048 + w * 256;                                   \
      int gi_ = gbase_ + off_ + lane4;                                  \
      gi_ = gi_ < 7999996 ? gi_ : 7999996;                              \
      gload_lds16(W + gi_, &Wb[buf_][off_]);                            \
    }                                                                   \
  } while (0)

__global__ __launch_bounds__(512) void stage1_kernel(
    const float* __restrict__ W, const float* __restrict__ ws_in,
    float* __restrict__ y) {
  const float* xTg = ws_in + WS_XT;  // [i][64] (global)
  const float* rT  = ws_in + WS_RT;  // [k][64]
  __shared__ float Wb[2][8192];      // 64 KB: 2 x (40 rows x 200 + pad)
  __shared__ float xTl[12800];       // 51.2 KB: full xT

  int k = blockIdx.x;
  int tid = threadIdx.x;
  int lane = tid & 63;
  int w = __builtin_amdgcn_readfirstlane(tid >> 6);
  int jc = w & 3, bh = w >> 2;
  int j4 = lane & 15, bq = lane >> 4;
  int j0 = jc * 64 + j4 * 4;         // 4 j's: j0..j0+3 (pad beyond 200)
  int b0 = bh * 32 + bq * 8;         // 8 b's
  bool jok = j0 < 200;               // waves 3,7: only j4<2 live
  int joff = jok ? j0 : 0;           // clamp LDS read addr for dead lanes
  int kbase = k * 40000;
  int lane4 = lane * 4;

  // stage full xT -> LDS: 12800 floats = 50 wave-chunks of 256 floats
  for (int cc = w; cc < 50; cc += 8) {
    gload_lds16(xTg + cc * 256 + lane4, &xTl[cc * 256]);
  }
  S1_STAGE(0, 0);

  float acc[4][8];
#pragma unroll
  for (int jj = 0; jj < 4; jj++)
#pragma unroll
    for (int bb = 0; bb < 8; bb++) acc[jj][bb] = 0.f;

  for (int s = 0; s < 5; s++) {
    __syncthreads();                 // drains vmcnt -> slab s (and xT) ready
    if (s < 4) S1_STAGE((s + 1) & 1, s + 1);   // prefetch under compute
    const float* Ws = Wb[s & 1];
    const float* xrow = xTl + s * 40 * 64 + b0;
#pragma unroll 8
    for (int ri = 0; ri < 40; ri++) {
      float4 wv  = *(const float4*)(Ws + ri * 200 + joff);
      float4 xa  = *(const float4*)(xrow + ri * 64);
      float4 xb2 = *(const float4*)(xrow + ri * 64 + 4);
      float wc[4] = {wv.x, wv.y, wv.z, wv.w};
      float xv[8] = {xa.x, xa.y, xa.z, xa.w, xb2.x, xb2.y, xb2.z, xb2.w};
#pragma unroll
      for (int jj = 0; jj < 4; jj++)
#pragma unroll
        for (int bb = 0; bb < 8; bb++)
          acc[jj][bb] += wc[jj] * xv[bb];
    }
  }

  if (jok) {
    float4 r0 = *(const float4*)(rT + k * 64 + b0);
    float4 r1 = *(const float4*)(rT + k * 64 + b0 + 4);
    float rv[8] = {r0.x, r0.y, r0.z, r0.w, r1.x, r1.y, r1.z, r1.w};
#pragma unroll
    for (int jj = 0; jj < 4; jj++) {
      float* yo = y + ((j0 + jj) * 200 + k) * 64 + b0;   // j-major
      float4 o0 = make_float4(acc[jj][0] * rv[0], acc[jj][1] * rv[1],
                              acc[jj][2] * rv[2], acc[jj][3] * rv[3]);
      float4 o1 = make_float4(acc[jj][4] * rv[4], acc[jj][5] * rv[5],
                              acc[jj][6] * rv[6], acc[jj][7] * rv[7]);
      *(float4*)(yo) = o0;
      *(float4*)(yo + 4) = o1;
    }
  }
}

// ---------------------------------------------------------------------------
// Kernel C v3: STREAMING reduce over j-major y. Block j owns the contiguous
// 51.2 KB span y[j][0..200][64]; thread (kq,b) sums 50 k at 256-B stride
// within a contiguous 12.8 KB window (was: 50 loads at 51.2 KB stride
// scattered over 10 MB). unroll 10 for ILP; rest identical.
// ---------------------------------------------------------------------------
__global__ __launch_bounds__(256) void reduce_bn1_kernel(
    const float* __restrict__ y, const float* __restrict__ bn1g,
    const float* __restrict__ bn1b, float* __restrict__ ws) {
  int j = blockIdx.x;
  int tid = threadIdx.x, b = tid & 63, kq = tid >> 6;

  float s = 0.f;
  const float* yp = y + (j * 200 + kq * 50) * 64 + b;
#pragma unroll 10
  for (int k = 0; k < 50; k++) s += yp[k * 64];

  __shared__ float part[256];
  part[tid] = s;
  __syncthreads();
  if (tid < 64) {
    float v = part[tid] + part[64 + tid] + part[128 + tid] + part[192 + tid];
    float sum = v, sq = v * v;
#pragma unroll
    for (int o = 32; o > 0; o >>= 1) {
      sum += __shfl_xor(sum, o, 64);
      sq  += __shfl_xor(sq,  o, 64);
    }
    float mean = sum * (1.f / 64.f);
    float var  = sq  * (1.f / 64.f) - mean * mean;
    float inv  = __builtin_amdgcn_rsqf(var + BN_EPS);
    float g    = bn1g[j] * inv;
    float be   = bn1b[j] - mean * g;
    float xv   = g * v + be;
    unsigned short h, l;
    split2(xv, h, l);
    unsigned short* xh = (unsigned short*)(ws + WS_X2BH);
    unsigned short* xl = (unsigned short*)(ws + WS_X2BL);
    xh[tid * 256 + j] = h;
    xl[tid * 256 + j] = l;
  }
}

// ---------------------------------------------------------------------------
// Final (R6 version, measured-best 47.1 us; pinned after 5 failed
// restructures R2/R3/R4/R5/R7 — occupancy is NOT its limiter): score_l via
// split-bf16 MFMA 16x16x32; score_n via R8 loop on the C-fragment mapping.
// grid 625, 256 thr = 4 waves.
// ---------------------------------------------------------------------------
__global__ __launch_bounds__(256, 4) void final_kernel(
    const float* __restrict__ E, const float* __restrict__ lits,
    const float* __restrict__ ws, float* __restrict__ out) {
  const float* taP = ws + WS_TAP;
  const float* wP  = ws + WS_WP;
  const float* sl  = ws + WS_SL;
  const unsigned short* x2bh = (const unsigned short*)(ws + WS_X2BH);
  const unsigned short* x2bl = (const unsigned short*)(ws + WS_X2BL);

  __shared__ float SM[9216];                 // 36864 B arena
  unsigned short* Ah = (unsigned short*)SM;  // [64][72] bf16
  unsigned short* Al = Ah + 4608;
  unsigned short* Bh = Ah + 9216;
  unsigned short* Bl = Ah + 13824;

  int n0 = blockIdx.x * 64;
  int tid = threadIdx.x;
  int lane = tid & 63;
  int w = __builtin_amdgcn_readfirstlane(tid >> 6);
  int ln = lane & 15;
  int quad = lane >> 4;

  f4v acc[4];
#pragma unroll
  for (int t = 0; t < 4; t++) acc[t] = (f4v){0.f, 0.f, 0.f, 0.f};

  // ---- score_l: 4 K-slabs of 64 ----
  for (int q = 0; q < 4; q++) {
    int k0 = q * 64;
    __syncthreads();
    // stage E slab -> Ah/Al (split-bf16 on the fly)
#pragma unroll
    for (int it = 0; it < 4; it++) {
      int idx = tid + it * 256;
      int row = idx >> 4, c4 = idx & 15, cc = c4 * 4;
      float4 v = make_float4(0.f, 0.f, 0.f, 0.f);
      if (k0 + cc < 200) v = *(const float4*)(E + (n0 + row) * D1C + k0 + cc);
      unsigned short h0, l0, h1, l1, h2, l2, h3, l3;
      split2(v.x, h0, l0); split2(v.y, h1, l1);
      split2(v.z, h2, l2); split2(v.w, h3, l3);
      *(ushort4*)(Ah + row * 72 + cc) = make_ushort4(h0, h1, h2, h3);
      *(ushort4*)(Al + row * 72 + cc) = make_ushort4(l0, l1, l2, l3);
    }
    // stage x2B slab -> Bh/Bl (straight copy; K-pad already zeroed)
#pragma unroll
    for (int it = 0; it < 4; it++) {
      int idx = tid + it * 256;
      int row = idx >> 4, c4 = idx & 15;
      *(ushort4*)(Bh + row * 72 + c4 * 4) =
          *(const ushort4*)(x2bh + row * 256 + k0 + c4 * 4);
      *(ushort4*)(Bl + row * 72 + c4 * 4) =
          *(const ushort4*)(x2bl + row * 256 + k0 + c4 * 4);
    }
    __syncthreads();

    const unsigned short* Ab  = Ah + (16 * w + ln) * 72 + quad * 8;
    const unsigned short* Alb = Al + (16 * w + ln) * 72 + quad * 8;
#pragma unroll
    for (int ks = 0; ks < 64; ks += 32) {
      s8v ah = *(const s8v*)(Ab + ks);
      s8v al = *(const s8v*)(Alb + ks);
#pragma unroll
      for (int t = 0; t < 4; t++) {
        s8v bh = *(const s8v*)(Bh + (16 * t + ln) * 72 + quad * 8 + ks);
        s8v bl = *(const s8v*)(Bl + (16 * t + ln) * 72 + quad * 8 + ks);
        acc[t] = __builtin_amdgcn_mfma_f32_16x16x32_bf16(ah, bh, acc[t], 0, 0, 0);
        acc[t] = __builtin_amdgcn_mfma_f32_16x16x32_bf16(al, bh, acc[t], 0, 0, 0);
        acc[t] = __builtin_amdgcn_mfma_f32_16x16x32_bf16(ah, bl, acc[t], 0, 0, 0);
      }
    }
  }

  // ---- phase B: score_n on the C-fragment mapping ----
  float* Llds = SM;           // [64][68] scaled lits, rows=l, cols=n-local
  float* TAl  = SM + 4352;    // [32][64] ta half (b-permuted)
  float* Wl   = SM + 6400;    // [32][64]
  int nlb = 16 * w + 4 * quad;

  __syncthreads();
#pragma unroll
  for (int it = 0; it < 4; it++) {
    int idx = tid + it * 256;
    int row = idx >> 4, c4 = idx & 15;
    float4 v = *(const float4*)(lits + (n0 + row) * LLC + c4 * 4);
    int l = c4 * 4;
    Llds[(l + 0) * 68 + row] = v.x * sl[l + 0];
    Llds[(l + 1) * 68 + row] = v.y * sl[l + 1];
    Llds[(l + 2) * 68 + row] = v.z * sl[l + 2];
    Llds[(l + 3) * 68 + row] = v.w * sl[l + 3];
  }

  for (int h = 0; h < 2; h++) {
    __syncthreads();          // h=0: Llds staged; h=1: previous reads done
#pragma unroll
    for (int it = 0; it < 2; it++) {
      int idx = tid + it * 256;
      ((float4*)TAl)[idx] = ((const float4*)(taP + h * 2048))[idx];
      ((float4*)Wl)[idx]  = ((const float4*)(wP  + h * 2048))[idx];
    }
    __syncthreads();
    for (int ll = 0; ll < 32; ll++) {
      float4 Lv = *(const float4*)(Llds + (h * 32 + ll) * 68 + nlb);
      float4 ta = *(const float4*)(TAl + ll * 64 + 4 * ln);
      float4 wv = *(const float4*)(Wl  + ll * 64 + 4 * ln);
      float Lc[4]  = {Lv.x, Lv.y, Lv.z, Lv.w};
      float tac[4] = {ta.x, ta.y, ta.z, ta.w};
      float wvc[4] = {wv.x, wv.y, wv.z, wv.w};
      float n2[4];
#pragma unroll
      for (int r = 0; r < 4; r++) n2[r] = -Lc[r] * Lc[r];
#pragma unroll
      for (int t = 0; t < 4; t++) {
#pragma unroll
        for (int r = 0; r < 4; r++) {
          acc[t][r] += wvc[t] *
              __builtin_amdgcn_exp2f(__builtin_fmaf(tac[t], Lc[r], n2[r]));
        }
      }
    }
  }

  // ---- sigmoid + float4 stores (4 consecutive n per b-row) ----
#pragma unroll
  for (int t = 0; t < 4; t++) {
    float4 o;
    o.x = __builtin_amdgcn_rcpf(1.f + __builtin_amdgcn_exp2f(-LOG2E * acc[t][0]));
    o.y = __builtin_amdgcn_rcpf(1.f + __builtin_amdgcn_exp2f(-LOG2E * acc[t][1]));
    o.z = __builtin_amdgcn_rcpf(1.f + __builtin_amdgcn_exp2f(-LOG2E * acc[t][2]));
    o.w = __builtin_amdgcn_rcpf(1.f + __builtin_amdgcn_exp2f(-LOG2E * acc[t][3]));
    *(float4*)(out + (size_t)(16 * t + ln) * NEC + n0 + nlb) = o;
  }
}

// ---------------------------------------------------------------------------
extern "C" void kernel_launch(void* const* d_in, const int* in_sizes, int n_in,
                              void* d_out, int out_size, void* d_ws, size_t ws_size,
                              hipStream_t stream) {
  (void)in_sizes; (void)n_in; (void)out_size; (void)ws_size;
  const int*   e1    = (const int*)d_in[0];
  const int*   ri    = (const int*)d_in[1];
  const float* E     = (const float*)d_in[2];
  const float* R     = (const float*)d_in[3];
  const float* W     = (const float*)d_in[4];
  const float* lits  = (const float*)d_in[5];
  const float* c     = (const float*)d_in[6];
  const float* var_l = (const float*)d_in[7];
  const float* nf    = (const float*)d_in[8];
  const float* bn0g  = (const float*)d_in[9];
  const float* bn0b  = (const float*)d_in[10];
  const float* bn1g  = (const float*)d_in[11];
  const float* bn1b  = (const float*)d_in[12];
  float* out = (float*)d_out;
  float* ws  = (float*)d_ws;
  float* y   = ws + WS_Y;

  prep_kernel<<<16, 256, 0, stream>>>(e1, ri, E, R, lits, c, var_l, nf,
                                      bn0g, bn0b, ws);
  stage1_kernel<<<200, 512, 0, stream>>>(W, ws, y);
  reduce_bn1_kernel<<<200, 256, 0, stream>>>(y, bn1g, bn1b, ws);
  final_kernel<<<625, 256, 0, stream>>>(E, lits, ws, out);
}